// Round 12
// baseline (736.366 us; speedup 1.0000x reference)
//
#include <hip/hip_runtime.h>
#include <hip/hip_bf16.h>
#include <hip/hip_cooperative_groups.h>
#include <math.h>

#define Hdim 128
#define NBq 8
#define SIq 16

namespace cg = cooperative_groups;

typedef __attribute__((ext_vector_type(8))) short short8x;
typedef __attribute__((ext_vector_type(4))) float f32x4;

__device__ inline unsigned short f2b(float f) {
  unsigned int u = __float_as_uint(f);
  return (unsigned short)((u + 0x7fffu + ((u >> 16) & 1u)) >> 16);   // RNE
}
__device__ inline unsigned int pack2(float lo, float hi) {
  return (unsigned int)f2b(lo) | ((unsigned int)f2b(hi) << 16);
}

// ---------------- fused preprocessing: gather | W-bdd transpose | dense-W transpose | dst histogram ----------------
__global__ __launch_bounds__(256) void k_pre(
    const float* __restrict__ emb, const int* __restrict__ ids, float* __restrict__ x0,
    const float* __restrict__ W0, unsigned short* __restrict__ Wt0,
    const float* __restrict__ W1, unsigned short* __restrict__ Wt1, int w0elems,
    const float* __restrict__ l0, const float* __restrict__ l1,
    const float* __restrict__ Wi, const float* __restrict__ Wo, const float* __restrict__ Wz,
    unsigned short* __restrict__ l0t, unsigned short* __restrict__ l1t,
    unsigned short* __restrict__ Wit, unsigned short* __restrict__ Wot,
    unsigned short* __restrict__ Wzt,
    const int* __restrict__ dst, int* __restrict__ cnt, int E,
    int b1, int b2, int b3) {
  int bx = blockIdx.x, t = threadIdx.x;
  if (bx < b1) {
    int idx = bx * 256 + t;
    int n = idx >> 5, c4 = idx & 31;
    int s = ids[n];
    ((float4*)x0)[(size_t)n * 32 + c4] = ((const float4*)emb)[(size_t)s * 32 + c4];
  } else if (bx < b2) {
    int idx = (bx - b1) * 256 + t;
    const float* W = (idx < w0elems) ? W0 : W1;
    unsigned short* Wt = (idx < w0elems) ? Wt0 : Wt1;
    int local = (idx < w0elems) ? idx : idx - w0elems;
    int rb = local >> 8, io = local & 255;
    int i = io >> 4, o = io & 15;
    Wt[(size_t)rb * 256 + o * 16 + i] = f2b(W[(size_t)rb * 256 + i * 16 + o]);
  } else if (bx < b3) {
    int idx = (bx - b2) * 256 + t;
    if (idx < 65536) {
      int w = idx >> 14, local = idx & 16383;
      const float* in = (w == 0) ? l0 : (w == 1) ? l1 : (w == 2) ? Wi : Wo;
      unsigned short* out = (w == 0) ? l0t : (w == 1) ? l1t : (w == 2) ? Wit : Wot;
      int n = local >> 7, k = local & 127;
      out[local] = f2b(in[k * 128 + n]);
    } else {
      int local = idx - 65536;
      int n = local >> 7, k = local & 127;
      Wzt[local] = f2b(Wz[k * 256 + n]);
    }
  } else {
    int e = (bx - b3) * 256 + t;
    if (e < E) atomicAdd(&cnt[dst[e]], 1);
  }
}

// ---------------- dst CSR: scan / scatter-permute ----------------
__global__ __launch_bounds__(1024) void k_scan(const int* __restrict__ cnt,
                                               int* __restrict__ off,
                                               int* __restrict__ cur, int N, int E) {
  __shared__ int part[1024];
  int t = threadIdx.x;
  int ipt = N / 1024;
  int base = t * ipt;
  int loc[8];
  int s = 0;
  for (int i = 0; i < ipt; ++i) { loc[i] = s; s += cnt[base + i]; }
  part[t] = s;
  __syncthreads();
  for (int d = 1; d < 1024; d <<= 1) {
    int v = part[t];
    int add = (t >= d) ? part[t - d] : 0;
    __syncthreads();
    part[t] = v + add;
    __syncthreads();
  }
  int pre = (t == 0) ? 0 : part[t - 1];
  for (int i = 0; i < ipt; ++i) {
    int o = pre + loc[i];
    off[base + i] = o;
    cur[base + i] = o;
  }
  if (t == 0) off[N] = E;
}

__global__ void k_scatter(const int* __restrict__ src, const int* __restrict__ dst,
                          const int* __restrict__ et, const float* __restrict__ norm,
                          int* __restrict__ cur, int* __restrict__ psrc,
                          int* __restrict__ pet, float* __restrict__ pnorm, int E) {
  int e = blockIdx.x * blockDim.x + threadIdx.x;
  if (e >= E) return;
  int p = atomicAdd(&cur[dst[e]], 1);
  psrc[p] = src[e];
  pet[p]  = et[e];
  pnorm[p] = norm[e];
}

// ---------------- segment-reduce edge aggregation, bf16 W, 2 nodes/block ----------------
// Same verified inner structure as the 41.6us k_edge4 (LDS-staged x rows,
// serialized per-edge W loads). Only the block shape changes: 256 threads =
// 2 dst nodes, chunk count padded to the block max so __syncthreads stays
// uniform. Goal: occupancy 50% -> ~100% (latency-bound kernel).
#define BF_LO(u) __uint_as_float((u) << 16)
#define BF_HI(u) __uint_as_float((u) & 0xffff0000u)
__global__ __launch_bounds__(256) void k_edge7(
    const float* __restrict__ h, const unsigned short* __restrict__ Wt,
    const int* __restrict__ off, const int* __restrict__ psrc,
    const int* __restrict__ pet, const float* __restrict__ pnorm,
    float* __restrict__ agg) {
  int t = threadIdx.x;
  int half = t >> 7;
  int f = t & 127;
  int b = f >> 4, o = f & 15;
  int nb = blockIdx.x * 2;
  int c0 = off[nb], c1 = off[nb + 1], c2 = off[nb + 2];
  int n  = nb + half;
  int j0 = half ? c1 : c0;
  int j1 = half ? c2 : c1;
  int chunks = (max(c1 - c0, c2 - c1) + 7) >> 3;   // block-uniform
  __shared__ float xs[2][8][Hdim];
  float acc = 0.f;
  for (int cb = 0; cb < chunks; ++cb) {
    int j = j0 + cb * 8;
    int m = min(8, j1 - j);          // may be <= 0 for the shorter half
    for (int q = 0; q < m; ++q)
      xs[half][q][f] = h[(size_t)psrc[j + q] * Hdim + f];
    __syncthreads();
    for (int q = 0; q < m; ++q) {
      int r = pet[j + q];
      float nv = pnorm[j + q];
      const uint4* wp = (const uint4*)(Wt + ((size_t)r * NBq + b) * 256 + o * 16);
      uint4 wa = wp[0], wb = wp[1];
      const float4* xp = (const float4*)(&xs[half][q][b * SIq]);
      float4 x0 = xp[0], x1 = xp[1], x2 = xp[2], x3 = xp[3];
      float a = x0.x*BF_LO(wa.x) + x0.y*BF_HI(wa.x) + x0.z*BF_LO(wa.y) + x0.w*BF_HI(wa.y)
              + x1.x*BF_LO(wa.z) + x1.y*BF_HI(wa.z) + x1.z*BF_LO(wa.w) + x1.w*BF_HI(wa.w)
              + x2.x*BF_LO(wb.x) + x2.y*BF_HI(wb.x) + x2.z*BF_LO(wb.y) + x2.w*BF_HI(wb.y)
              + x3.x*BF_LO(wb.z) + x3.y*BF_HI(wb.z) + x3.z*BF_LO(wb.w) + x3.w*BF_HI(wb.w);
      acc = fmaf(a, nv, acc);
    }
    __syncthreads();
  }
  agg[(size_t)n * Hdim + f] = acc;
}

// ---------------- MFMA bf16 GEMM device body: C[*,128] = A[*,128]@B + addm + bias + relu ----------------
// tile in [0,512): bm=(tile&255)*32, bn=(tile>>8)*64. sm needs 26112 B.
__device__ void d_bgemm(char* sm, const float* __restrict__ A,
                        const unsigned short* __restrict__ Bt,
                        const float* __restrict__ Gsrc, float* __restrict__ C,
                        const float* __restrict__ addm, const float* __restrict__ bias,
                        int relu, float* __restrict__ gzero, int tile) {
  unsigned short (*Al)[136] = (unsigned short(*)[136])sm;
  unsigned short (*Bl)[136] = (unsigned short(*)[136])(sm + 32 * 136 * 2);
  int t = threadIdx.x;
  int bm = (tile & 255) * 32, bn = (tile >> 8) * 64;
  if (gzero && tile == 0) {
#pragma unroll
    for (int i = 0; i < 16; ++i)
      ((float4*)gzero)[t + 256 * i] = make_float4(0.f, 0.f, 0.f, 0.f);
  }
  {
    int r = t >> 3, c0 = (t & 7) << 4;
    const float4* ap = (const float4*)(A + (size_t)(bm + r) * Hdim + c0);
    float4 a0 = ap[0], a1 = ap[1], a2 = ap[2], a3 = ap[3];
    uint4 p0 = { pack2(a0.x, a0.y), pack2(a0.z, a0.w), pack2(a1.x, a1.y), pack2(a1.z, a1.w) };
    uint4 p1 = { pack2(a2.x, a2.y), pack2(a2.z, a2.w), pack2(a3.x, a3.y), pack2(a3.z, a3.w) };
    *(uint4*)&Al[r][c0]     = p0;
    *(uint4*)&Al[r][c0 + 8] = p1;
  }
  if (Bt) {
    int n = t >> 2, k0 = (t & 3) << 5;
    const uint4* bp = (const uint4*)(Bt + (size_t)(bn + n) * Hdim + k0);
    uint4 b0 = bp[0], b1 = bp[1], b2 = bp[2], b3 = bp[3];
    *(uint4*)&Bl[n][k0]      = b0;
    *(uint4*)&Bl[n][k0 + 8]  = b1;
    *(uint4*)&Bl[n][k0 + 16] = b2;
    *(uint4*)&Bl[n][k0 + 24] = b3;
  } else {
    int n = t & 63, kb = (t >> 6) << 5;
    for (int i = 0; i < 32; ++i) {
      int k = kb + i;
      Bl[n][k] = f2b(Gsrc[(size_t)k * 128 + bn + n]);
    }
  }
  __syncthreads();
  int wv = t >> 6, ln = t & 63;
  int mt = wv & 1;
  int nt0 = (wv >> 1) << 1;
  int lm = ln & 15, lk = ln >> 4;
  f32x4 acc0 = {0.f, 0.f, 0.f, 0.f}, acc1 = {0.f, 0.f, 0.f, 0.f};
#pragma unroll
  for (int ks = 0; ks < 4; ++ks) {
    short8x af = *(const short8x*)&Al[mt * 16 + lm][ks * 32 + lk * 8];
    short8x bf0 = *(const short8x*)&Bl[nt0 * 16 + lm][ks * 32 + lk * 8];
    short8x bf1 = *(const short8x*)&Bl[(nt0 + 1) * 16 + lm][ks * 32 + lk * 8];
    acc0 = __builtin_amdgcn_mfma_f32_16x16x32_bf16(af, bf0, acc0, 0, 0, 0);
    acc1 = __builtin_amdgcn_mfma_f32_16x16x32_bf16(af, bf1, acc1, 0, 0, 0);
  }
  int gcol0 = bn + nt0 * 16 + lm;
  int gcol1 = gcol0 + 16;
  float b0v = bias ? bias[gcol0] : 0.f;
  float b1v = bias ? bias[gcol1] : 0.f;
#pragma unroll
  for (int reg = 0; reg < 4; ++reg) {
    int grow = bm + mt * 16 + lk * 4 + reg;
    size_t o0 = (size_t)grow * Hdim + gcol0;
    size_t o1 = (size_t)grow * Hdim + gcol1;
    float v0 = acc0[reg] + b0v;
    float v1 = acc1[reg] + b1v;
    if (addm) { v0 += addm[o0]; v1 += addm[o1]; }
    if (relu) { v0 = fmaxf(v0, 0.f); v1 = fmaxf(v1, 0.f); }
    C[o0] = v0;
    C[o1] = v1;
  }
}

__global__ __launch_bounds__(256) void k_bgemm(
    const float* __restrict__ A, const unsigned short* __restrict__ Bt,
    const float* __restrict__ Gsrc, float* __restrict__ C,
    const float* __restrict__ addm, const float* __restrict__ bias,
    int relu, float* __restrict__ gzero) {
  __shared__ char sm[26112];
  d_bgemm(sm, A, Bt, Gsrc, C, addm, bias, relu, gzero,
          blockIdx.x + (blockIdx.y << 8));
}

// ---------------- MFMA bf16 zml GEMM + reparameterization device body (sm 43520 B) ----------------
__device__ void d_bgemm_z(char* sm, const float* __restrict__ A,
                          const unsigned short* __restrict__ Wzt,
                          const float* __restrict__ bz, const float* __restrict__ eps,
                          float* __restrict__ Z, int tile) {
  unsigned short (*Al)[136] = (unsigned short(*)[136])sm;
  unsigned short (*Bm)[136] = (unsigned short(*)[136])(sm + 8704);
  unsigned short (*Bl)[136] = (unsigned short(*)[136])(sm + 8704 + 17408);
  int t = threadIdx.x;
  int bm = (tile & 255) * 32, bn = (tile >> 8) * 64;
  {
    int r = t >> 3, c0 = (t & 7) << 4;
    const float4* ap = (const float4*)(A + (size_t)(bm + r) * Hdim + c0);
    float4 a0 = ap[0], a1 = ap[1], a2 = ap[2], a3 = ap[3];
    uint4 p0 = { pack2(a0.x, a0.y), pack2(a0.z, a0.w), pack2(a1.x, a1.y), pack2(a1.z, a1.w) };
    uint4 p1 = { pack2(a2.x, a2.y), pack2(a2.z, a2.w), pack2(a3.x, a3.y), pack2(a3.z, a3.w) };
    *(uint4*)&Al[r][c0]     = p0;
    *(uint4*)&Al[r][c0 + 8] = p1;
  }
  {
    int n = t >> 2, k0 = (t & 3) << 5;
    const uint4* mp = (const uint4*)(Wzt + (size_t)(bn + n) * Hdim + k0);
    const uint4* lp = (const uint4*)(Wzt + (size_t)(bn + 128 + n) * Hdim + k0);
    uint4 m0 = mp[0], m1 = mp[1], m2 = mp[2], m3 = mp[3];
    uint4 l0 = lp[0], l1 = lp[1], l2 = lp[2], l3 = lp[3];
    *(uint4*)&Bm[n][k0]      = m0; *(uint4*)&Bm[n][k0 + 8]  = m1;
    *(uint4*)&Bm[n][k0 + 16] = m2; *(uint4*)&Bm[n][k0 + 24] = m3;
    *(uint4*)&Bl[n][k0]      = l0; *(uint4*)&Bl[n][k0 + 8]  = l1;
    *(uint4*)&Bl[n][k0 + 16] = l2; *(uint4*)&Bl[n][k0 + 24] = l3;
  }
  __syncthreads();
  int wv = t >> 6, ln = t & 63;
  int mt = wv & 1;
  int nt0 = (wv >> 1) << 1;
  int lm = ln & 15, lk = ln >> 4;
  f32x4 am0 = {0,0,0,0}, am1 = {0,0,0,0}, al0 = {0,0,0,0}, al1 = {0,0,0,0};
#pragma unroll
  for (int ks = 0; ks < 4; ++ks) {
    short8x af = *(const short8x*)&Al[mt * 16 + lm][ks * 32 + lk * 8];
    short8x bm0 = *(const short8x*)&Bm[nt0 * 16 + lm][ks * 32 + lk * 8];
    short8x bm1 = *(const short8x*)&Bm[(nt0 + 1) * 16 + lm][ks * 32 + lk * 8];
    short8x bl0 = *(const short8x*)&Bl[nt0 * 16 + lm][ks * 32 + lk * 8];
    short8x bl1 = *(const short8x*)&Bl[(nt0 + 1) * 16 + lm][ks * 32 + lk * 8];
    am0 = __builtin_amdgcn_mfma_f32_16x16x32_bf16(af, bm0, am0, 0, 0, 0);
    am1 = __builtin_amdgcn_mfma_f32_16x16x32_bf16(af, bm1, am1, 0, 0, 0);
    al0 = __builtin_amdgcn_mfma_f32_16x16x32_bf16(af, bl0, al0, 0, 0, 0);
    al1 = __builtin_amdgcn_mfma_f32_16x16x32_bf16(af, bl1, al1, 0, 0, 0);
  }
  int gcol0 = bn + nt0 * 16 + lm;
  int gcol1 = gcol0 + 16;
  float bm0v = bz[gcol0], bm1v = bz[gcol1];
  float bl0v = bz[128 + gcol0], bl1v = bz[128 + gcol1];
#pragma unroll
  for (int reg = 0; reg < 4; ++reg) {
    int grow = bm + mt * 16 + lk * 4 + reg;
    size_t o0 = (size_t)grow * Hdim + gcol0;
    size_t o1 = (size_t)grow * Hdim + gcol1;
    Z[o0] = am0[reg] + bm0v + expf(al0[reg] + bl0v) * eps[o0];
    Z[o1] = am1[reg] + bm1v + expf(al1[reg] + bl1v) * eps[o1];
  }
}

// ---------------- xty device body: G += X^T @ Y over K-slice (sm 4096 B) ----------------
// tile in [0,128): kslice = tile & 31, quad = tile >> 5.
__device__ void d_xty(char* sm, const float* __restrict__ X, const float* __restrict__ Y,
                      float* __restrict__ G, int N, int tile) {
  float (*xs)[64] = (float(*)[64])sm;
  float (*ys)[64] = (float(*)[64])(sm + 2048);
  int t  = threadIdx.x;
  int tx = t & 15, ty = t >> 4;
  int quad = tile >> 5;
  int qr = quad >> 1, qc = quad & 1;
  int KC = N / 32;
  int k0 = (tile & 31) * KC;
  int m  = t >> 7, li = t & 127;
  int lr = li >> 4, lc = (li & 15) << 2;
  const float* S = m ? Y : X;
  int coff = (m ? qc : qr) * 64;
  float acc[4][4] = {};
  for (int kb = 0; kb < KC; kb += 8) {
    float4 v = *(const float4*)(S + (size_t)(k0 + kb + lr) * Hdim + coff + lc);
    __syncthreads();
    if (m) *(float4*)&ys[lr][lc] = v; else *(float4*)&xs[lr][lc] = v;
    __syncthreads();
#pragma unroll
    for (int kk = 0; kk < 8; ++kk) {
      float4 xv = *(const float4*)&xs[kk][ty << 2];
      float4 yv = *(const float4*)&ys[kk][tx << 2];
      acc[0][0] += xv.x * yv.x; acc[0][1] += xv.x * yv.y; acc[0][2] += xv.x * yv.z; acc[0][3] += xv.x * yv.w;
      acc[1][0] += xv.y * yv.x; acc[1][1] += xv.y * yv.y; acc[1][2] += xv.y * yv.z; acc[1][3] += xv.y * yv.w;
      acc[2][0] += xv.z * yv.x; acc[2][1] += xv.z * yv.y; acc[2][2] += xv.z * yv.z; acc[2][3] += xv.z * yv.w;
      acc[3][0] += xv.w * yv.x; acc[3][1] += xv.w * yv.y; acc[3][2] += xv.w * yv.z; acc[3][3] += xv.w * yv.w;
    }
  }
  int grow = qr * 64 + (ty << 2);
  int gcol = qc * 64 + (tx << 2);
#pragma unroll
  for (int r = 0; r < 4; ++r)
#pragma unroll
    for (int c = 0; c < 4; ++c)
      atomicAdd(&G[(size_t)(grow + r) * Hdim + gcol + c], acc[r][c]);
}

// ---------------- cooperative dense tail: h2, z, C1, G1, h3, C2, G2, out ----------------
// 512 blocks x 256 threads = 2 blocks/CU (LDS 43520 B/block -> co-resident).
__global__ __launch_bounds__(256, 1) void k_tail(
    float* B1p, float* B2p, float* B3p, const float* X0, const float* AGG, float* G,
    const unsigned short* l1t, const unsigned short* Wit, const unsigned short* Wot,
    const unsigned short* Wzt, const float* b1, const float* bz, const float* eps,
    const float* bi, const float* hbi, const float* bo, const float* hbo,
    float* out, int N) {
  __shared__ char sm[43520];
  cg::grid_group g = cg::this_grid();
  int tile = blockIdx.x;
  // P0: h2 = agg + b1 + h1@loop1 -> B2p
  d_bgemm(sm, B1p, l1t, nullptr, B2p, AGG, b1, 0, nullptr, tile);
  g.sync();
  // P1: z = mean + exp(log_std)*eps -> B1p
  d_bgemm_z(sm, B2p, Wzt, bz, eps, B1p, tile);
  g.sync();
  // P2: C1 = z@Wi + bi + x0 -> B3p  (tile 0 zeroes G)
  d_bgemm(sm, B1p, Wit, nullptr, B3p, X0, bi, 0, G, tile);
  g.sync();
  // P3: G1 = z^T @ C1
  if (tile < 128) d_xty(sm, B1p, B3p, G, N, tile);
  g.sync();
  // P4: h3 = z@G1 + hbi -> B2p
  d_bgemm(sm, B1p, nullptr, G, B2p, nullptr, hbi, 0, nullptr, tile);
  g.sync();
  // P5: C2 = h3@Wo + bo + x0 -> B3p  (tile 0 zeroes G; all G reads done at P4 sync)
  d_bgemm(sm, B2p, Wot, nullptr, B3p, X0, bo, 0, G, tile);
  g.sync();
  // P6: G2 = h3^T @ C2
  if (tile < 128) d_xty(sm, B2p, B3p, G, N, tile);
  g.sync();
  // P7: out = h3@G2 + hbo
  d_bgemm(sm, B2p, nullptr, G, out, nullptr, hbo, 0, nullptr, tile);
}

extern "C" void kernel_launch(void* const* d_in, const int* in_sizes, int n_in,
                              void* d_out, int out_size, void* d_ws, size_t ws_size,
                              hipStream_t stream) {
  const int*   node_ids = (const int*)d_in[0];
  const int*   src      = (const int*)d_in[1];
  const int*   dst      = (const int*)d_in[2];
  const int*   et       = (const int*)d_in[3];
  const float* norm     = (const float*)d_in[4];
  const float* eps      = (const float*)d_in[5];
  const float* emb      = (const float*)d_in[6];
  const float* W0       = (const float*)d_in[7];
  const float* loop0    = (const float*)d_in[8];
  const float* b0       = (const float*)d_in[9];
  const float* W1       = (const float*)d_in[10];
  const float* loop1    = (const float*)d_in[11];
  const float* b1       = (const float*)d_in[12];
  const float* Wz       = (const float*)d_in[13];
  const float* bz       = (const float*)d_in[14];
  const float* Wi       = (const float*)d_in[15];
  const float* bi       = (const float*)d_in[16];
  const float* hbi      = (const float*)d_in[17];
  const float* Wo       = (const float*)d_in[18];
  const float* bo       = (const float*)d_in[19];
  const float* hbo      = (const float*)d_in[20];
  float* out = (float*)d_out;

  const int N  = in_sizes[0];   // 8192
  const int E  = in_sizes[1];   // 131072
  const int RB = in_sizes[7] / (SIq * SIq);   // NREL * NBq = 720

  char* ws = (char*)d_ws;
  const size_t MB = 1u << 20;
  const size_t KB = 1u << 10;
  float* X0   = (float*)(ws + 0 * MB);
  float* B1p  = (float*)(ws + 4 * MB);
  float* B2p  = (float*)(ws + 8 * MB);
  float* AGG  = (float*)(ws + 12 * MB);
  float* B3p  = (float*)(ws + 16 * MB);
  float* G    = (float*)(ws + 20 * MB);    // 64 KB
  int*   offp = (int*)(ws + 20 * MB + 256 * KB);
  int*   curp = (int*)(ws + 20 * MB + 512 * KB);
  int*   cntp = (int*)(ws + 20 * MB + 768 * KB);
  int*   psrc = (int*)(ws + 21 * MB);
  int*   pet  = (int*)(ws + 21 * MB + 512 * KB);
  float* pnrm = (float*)(ws + 22 * MB);
  unsigned short* Wt0 = (unsigned short*)(ws + 22 * MB + 512 * KB);  // 368 KB
  unsigned short* Wt1 = (unsigned short*)(ws + 23 * MB);             // 368 KB
  unsigned short* l0t = (unsigned short*)(ws + 24 * MB);             // 32 KB
  unsigned short* l1t = (unsigned short*)(ws + 24 * MB + 64 * KB);
  unsigned short* Wit = (unsigned short*)(ws + 24 * MB + 128 * KB);
  unsigned short* Wot = (unsigned short*)(ws + 24 * MB + 192 * KB);
  unsigned short* Wzt = (unsigned short*)(ws + 24 * MB + 256 * KB);  // 64 KB

  dim3 blk(256);

  // ---- fused preprocessing ----
  const int w0elems = RB * 256;                      // 184320
  const int gB   = (N * 32) / 256;                   // 1024
  const int wtbB = (2 * w0elems + 255) / 256;        // 1440
  const int wttB = 98304 / 256;                      // 384
  const int histB = (E + 255) / 256;                 // 512
  const int b1s = gB, b2s = gB + wtbB, b3s = gB + wtbB + wttB;
  hipMemsetAsync(cntp, 0, (size_t)N * sizeof(int), stream);
  k_pre<<<dim3(b3s + histB), blk, 0, stream>>>(
      emb, node_ids, X0, W0, Wt0, W1, Wt1, w0elems,
      loop0, loop1, Wi, Wo, Wz, l0t, l1t, Wit, Wot, Wzt,
      dst, cntp, E, b1s, b2s, b3s);
  k_scan<<<dim3(1), dim3(1024), 0, stream>>>(cntp, offp, curp, N, E);
  k_scatter<<<dim3((E + 255) / 256), blk, 0, stream>>>(src, dst, et, norm, curp,
                                                       psrc, pet, pnrm, E);

  // layer-0 edge aggregation
  k_edge7<<<dim3(N / 2), blk, 0, stream>>>(X0, Wt0, offp, psrc, pet, pnrm, AGG);
  // h1 = relu(agg + b0 + x0@loop0)
  k_bgemm<<<dim3(256, 2), blk, 0, stream>>>(X0, l0t, nullptr, B1p, AGG, b0, 1, nullptr);
  // layer-1 edge aggregation
  k_edge7<<<dim3(N / 2), blk, 0, stream>>>(B1p, Wt1, offp, psrc, pet, pnrm, AGG);
  // dense tail: h2, z, C1, G1, h3, C2, G2, out (one cooperative dispatch)
  {
    void* targs[] = {
      (void*)&B1p, (void*)&B2p, (void*)&B3p, (void*)&X0, (void*)&AGG, (void*)&G,
      (void*)&l1t, (void*)&Wit, (void*)&Wot, (void*)&Wzt,
      (void*)&b1, (void*)&bz, (void*)&eps, (void*)&bi, (void*)&hbi,
      (void*)&bo, (void*)&hbo, (void*)&out, (void*)&N
    };
    hipLaunchCooperativeKernel((const void*)k_tail, dim3(512), blk, targs, 0, stream);
  }
}

// Round 13
// 348.117 us; speedup vs baseline: 2.1153x; 2.1153x over previous
//
#include <hip/hip_runtime.h>
#include <hip/hip_bf16.h>
#include <math.h>

#define Hdim 128
#define NBq 8
#define SIq 16

typedef __attribute__((ext_vector_type(8))) short short8x;
typedef __attribute__((ext_vector_type(4))) float f32x4;

__device__ inline unsigned short f2b(float f) {
  unsigned int u = __float_as_uint(f);
  return (unsigned short)((u + 0x7fffu + ((u >> 16) & 1u)) >> 16);   // RNE
}
__device__ inline unsigned int pack2(float lo, float hi) {
  return (unsigned int)f2b(lo) | ((unsigned int)f2b(hi) << 16);
}

// ---------------- fused preprocessing: gather | W-bdd transpose | dense-W transpose | dst histogram ----------------
__global__ __launch_bounds__(256) void k_pre(
    const float* __restrict__ emb, const int* __restrict__ ids, float* __restrict__ x0,
    const float* __restrict__ W0, unsigned short* __restrict__ Wt0,
    const float* __restrict__ W1, unsigned short* __restrict__ Wt1, int w0elems,
    const float* __restrict__ l0, const float* __restrict__ l1,
    const float* __restrict__ Wi, const float* __restrict__ Wo, const float* __restrict__ Wz,
    unsigned short* __restrict__ l0t, unsigned short* __restrict__ l1t,
    unsigned short* __restrict__ Wit, unsigned short* __restrict__ Wot,
    unsigned short* __restrict__ Wzt,
    const int* __restrict__ dst, int* __restrict__ cnt, int E,
    int b1, int b2, int b3) {
  int bx = blockIdx.x, t = threadIdx.x;
  if (bx < b1) {
    int idx = bx * 256 + t;
    int n = idx >> 5, c4 = idx & 31;
    int s = ids[n];
    ((float4*)x0)[(size_t)n * 32 + c4] = ((const float4*)emb)[(size_t)s * 32 + c4];
  } else if (bx < b2) {
    int idx = (bx - b1) * 256 + t;
    const float* W = (idx < w0elems) ? W0 : W1;
    unsigned short* Wt = (idx < w0elems) ? Wt0 : Wt1;
    int local = (idx < w0elems) ? idx : idx - w0elems;
    int rb = local >> 8, io = local & 255;
    int i = io >> 4, o = io & 15;
    Wt[(size_t)rb * 256 + o * 16 + i] = f2b(W[(size_t)rb * 256 + i * 16 + o]);
  } else if (bx < b3) {
    int idx = (bx - b2) * 256 + t;
    if (idx < 65536) {
      int w = idx >> 14, local = idx & 16383;
      const float* in = (w == 0) ? l0 : (w == 1) ? l1 : (w == 2) ? Wi : Wo;
      unsigned short* out = (w == 0) ? l0t : (w == 1) ? l1t : (w == 2) ? Wit : Wot;
      int n = local >> 7, k = local & 127;
      out[local] = f2b(in[k * 128 + n]);
    } else {
      int local = idx - 65536;
      int n = local >> 7, k = local & 127;
      Wzt[local] = f2b(Wz[k * 256 + n]);
    }
  } else {
    int e = (bx - b3) * 256 + t;
    if (e < E) atomicAdd(&cnt[dst[e]], 1);
  }
}

// ---------------- dst CSR: scan / scatter-permute ----------------
__global__ __launch_bounds__(1024) void k_scan(const int* __restrict__ cnt,
                                               int* __restrict__ off,
                                               int* __restrict__ cur, int N, int E) {
  __shared__ int part[1024];
  int t = threadIdx.x;
  int ipt = N / 1024;
  int base = t * ipt;
  int loc[8];
  int s = 0;
  for (int i = 0; i < ipt; ++i) { loc[i] = s; s += cnt[base + i]; }
  part[t] = s;
  __syncthreads();
  for (int d = 1; d < 1024; d <<= 1) {
    int v = part[t];
    int add = (t >= d) ? part[t - d] : 0;
    __syncthreads();
    part[t] = v + add;
    __syncthreads();
  }
  int pre = (t == 0) ? 0 : part[t - 1];
  for (int i = 0; i < ipt; ++i) {
    int o = pre + loc[i];
    off[base + i] = o;
    cur[base + i] = o;
  }
  if (t == 0) off[N] = E;
}

__global__ void k_scatter(const int* __restrict__ src, const int* __restrict__ dst,
                          const int* __restrict__ et, const float* __restrict__ norm,
                          int* __restrict__ cur, int* __restrict__ psrc,
                          int* __restrict__ pet, float* __restrict__ pnorm, int E) {
  int e = blockIdx.x * blockDim.x + threadIdx.x;
  if (e >= E) return;
  int p = atomicAdd(&cur[dst[e]], 1);
  psrc[p] = src[e];
  pet[p]  = et[e];
  pnorm[p] = norm[e];
}

// ---------------- segment-reduce edge aggregation, bf16 W, 2 nodes/block ----------------
// Verified inner structure (LDS-staged x rows, serialized W loads); 256-thr
// blocks with 2 dst nodes for occupancy. R7 batched-prefetch / R10 no-LDS
// pipelining regressed -- do not re-attempt source-level load scheduling.
#define BF_LO(u) __uint_as_float((u) << 16)
#define BF_HI(u) __uint_as_float((u) & 0xffff0000u)
__global__ __launch_bounds__(256) void k_edge7(
    const float* __restrict__ h, const unsigned short* __restrict__ Wt,
    const int* __restrict__ off, const int* __restrict__ psrc,
    const int* __restrict__ pet, const float* __restrict__ pnorm,
    float* __restrict__ agg) {
  int t = threadIdx.x;
  int half = t >> 7;
  int f = t & 127;
  int b = f >> 4, o = f & 15;
  int nb = blockIdx.x * 2;
  int c0 = off[nb], c1 = off[nb + 1], c2 = off[nb + 2];
  int n  = nb + half;
  int j0 = half ? c1 : c0;
  int j1 = half ? c2 : c1;
  int chunks = (max(c1 - c0, c2 - c1) + 7) >> 3;   // block-uniform
  __shared__ float xs[2][8][Hdim];
  float acc = 0.f;
  for (int cb = 0; cb < chunks; ++cb) {
    int j = j0 + cb * 8;
    int m = min(8, j1 - j);          // may be <= 0 for the shorter half
    for (int q = 0; q < m; ++q)
      xs[half][q][f] = h[(size_t)psrc[j + q] * Hdim + f];
    __syncthreads();
    for (int q = 0; q < m; ++q) {
      int r = pet[j + q];
      float nv = pnorm[j + q];
      const uint4* wp = (const uint4*)(Wt + ((size_t)r * NBq + b) * 256 + o * 16);
      uint4 wa = wp[0], wb = wp[1];
      const float4* xp = (const float4*)(&xs[half][q][b * SIq]);
      float4 x0 = xp[0], x1 = xp[1], x2 = xp[2], x3 = xp[3];
      float a = x0.x*BF_LO(wa.x) + x0.y*BF_HI(wa.x) + x0.z*BF_LO(wa.y) + x0.w*BF_HI(wa.y)
              + x1.x*BF_LO(wa.z) + x1.y*BF_HI(wa.z) + x1.z*BF_LO(wa.w) + x1.w*BF_HI(wa.w)
              + x2.x*BF_LO(wb.x) + x2.y*BF_HI(wb.x) + x2.z*BF_LO(wb.y) + x2.w*BF_HI(wb.y)
              + x3.x*BF_LO(wb.z) + x3.y*BF_HI(wb.z) + x3.z*BF_LO(wb.w) + x3.w*BF_HI(wb.w);
      acc = fmaf(a, nv, acc);
    }
    __syncthreads();
  }
  agg[(size_t)n * Hdim + f] = acc;
}

// ---------------- MFMA bf16 GEMM: C[M,128] = A[M,128]@B + addm + bias + relu ----------------
__global__ __launch_bounds__(256) void k_bgemm(
    const float* __restrict__ A, const unsigned short* __restrict__ Bt,
    const float* __restrict__ Gsrc, float* __restrict__ C,
    const float* __restrict__ addm, const float* __restrict__ bias,
    int M, int Nc, int relu, float* __restrict__ gzero) {
  __shared__ unsigned short Al[32][136];
  __shared__ unsigned short Bl[64][136];
  int t = threadIdx.x;
  int bm = blockIdx.x * 32, bn = blockIdx.y * 64;
  if (gzero && blockIdx.x == 0 && blockIdx.y == 0) {
#pragma unroll
    for (int i = 0; i < 16; ++i)
      ((float4*)gzero)[t + 256 * i] = make_float4(0.f, 0.f, 0.f, 0.f);
  }
  {
    int r = t >> 3, c0 = (t & 7) << 4;
    const float4* ap = (const float4*)(A + (size_t)(bm + r) * Hdim + c0);
    float4 a0 = ap[0], a1 = ap[1], a2 = ap[2], a3 = ap[3];
    uint4 p0 = { pack2(a0.x, a0.y), pack2(a0.z, a0.w), pack2(a1.x, a1.y), pack2(a1.z, a1.w) };
    uint4 p1 = { pack2(a2.x, a2.y), pack2(a2.z, a2.w), pack2(a3.x, a3.y), pack2(a3.z, a3.w) };
    *(uint4*)&Al[r][c0]     = p0;
    *(uint4*)&Al[r][c0 + 8] = p1;
  }
  if (Bt) {
    int n = t >> 2, k0 = (t & 3) << 5;
    const uint4* bp = (const uint4*)(Bt + (size_t)(bn + n) * Hdim + k0);
    uint4 b0 = bp[0], b1 = bp[1], b2 = bp[2], b3 = bp[3];
    *(uint4*)&Bl[n][k0]      = b0;
    *(uint4*)&Bl[n][k0 + 8]  = b1;
    *(uint4*)&Bl[n][k0 + 16] = b2;
    *(uint4*)&Bl[n][k0 + 24] = b3;
  } else {
    int n = t & 63, kb = (t >> 6) << 5;
    for (int i = 0; i < 32; ++i) {
      int k = kb + i;
      Bl[n][k] = f2b(Gsrc[(size_t)k * 128 + bn + n]);
    }
  }
  __syncthreads();
  int wv = t >> 6, ln = t & 63;
  int mt = wv & 1;
  int nt0 = (wv >> 1) << 1;
  int lm = ln & 15, lk = ln >> 4;
  f32x4 acc0 = {0.f, 0.f, 0.f, 0.f}, acc1 = {0.f, 0.f, 0.f, 0.f};
#pragma unroll
  for (int ks = 0; ks < 4; ++ks) {
    short8x af = *(const short8x*)&Al[mt * 16 + lm][ks * 32 + lk * 8];
    short8x bf0 = *(const short8x*)&Bl[nt0 * 16 + lm][ks * 32 + lk * 8];
    short8x bf1 = *(const short8x*)&Bl[(nt0 + 1) * 16 + lm][ks * 32 + lk * 8];
    acc0 = __builtin_amdgcn_mfma_f32_16x16x32_bf16(af, bf0, acc0, 0, 0, 0);
    acc1 = __builtin_amdgcn_mfma_f32_16x16x32_bf16(af, bf1, acc1, 0, 0, 0);
  }
  int gcol0 = bn + nt0 * 16 + lm;
  int gcol1 = gcol0 + 16;
  float b0v = bias ? bias[gcol0] : 0.f;
  float b1v = bias ? bias[gcol1] : 0.f;
#pragma unroll
  for (int reg = 0; reg < 4; ++reg) {
    int grow = bm + mt * 16 + lk * 4 + reg;
    size_t o0 = (size_t)grow * Nc + gcol0;
    size_t o1 = (size_t)grow * Nc + gcol1;
    float v0 = acc0[reg] + b0v;
    float v1 = acc1[reg] + b1v;
    if (addm) { v0 += addm[o0]; v1 += addm[o1]; }
    if (relu) { v0 = fmaxf(v0, 0.f); v1 = fmaxf(v1, 0.f); }
    C[o0] = v0;
    C[o1] = v1;
  }
}

// ---------------- MFMA bf16 zml GEMM fused with reparameterization ----------------
__global__ __launch_bounds__(256) void k_bgemm_z(
    const float* __restrict__ A, const unsigned short* __restrict__ Wzt,
    const float* __restrict__ bz, const float* __restrict__ eps,
    float* __restrict__ Z, int M) {
  __shared__ unsigned short Al[32][136];
  __shared__ unsigned short Bm[64][136];
  __shared__ unsigned short Bl[64][136];
  int t = threadIdx.x;
  int bm = blockIdx.x * 32, bn = blockIdx.y * 64;
  {
    int r = t >> 3, c0 = (t & 7) << 4;
    const float4* ap = (const float4*)(A + (size_t)(bm + r) * Hdim + c0);
    float4 a0 = ap[0], a1 = ap[1], a2 = ap[2], a3 = ap[3];
    uint4 p0 = { pack2(a0.x, a0.y), pack2(a0.z, a0.w), pack2(a1.x, a1.y), pack2(a1.z, a1.w) };
    uint4 p1 = { pack2(a2.x, a2.y), pack2(a2.z, a2.w), pack2(a3.x, a3.y), pack2(a3.z, a3.w) };
    *(uint4*)&Al[r][c0]     = p0;
    *(uint4*)&Al[r][c0 + 8] = p1;
  }
  {
    int n = t >> 2, k0 = (t & 3) << 5;
    const uint4* mp = (const uint4*)(Wzt + (size_t)(bn + n) * Hdim + k0);
    const uint4* lp = (const uint4*)(Wzt + (size_t)(bn + 128 + n) * Hdim + k0);
    uint4 m0 = mp[0], m1 = mp[1], m2 = mp[2], m3 = mp[3];
    uint4 l0 = lp[0], l1 = lp[1], l2 = lp[2], l3 = lp[3];
    *(uint4*)&Bm[n][k0]      = m0; *(uint4*)&Bm[n][k0 + 8]  = m1;
    *(uint4*)&Bm[n][k0 + 16] = m2; *(uint4*)&Bm[n][k0 + 24] = m3;
    *(uint4*)&Bl[n][k0]      = l0; *(uint4*)&Bl[n][k0 + 8]  = l1;
    *(uint4*)&Bl[n][k0 + 16] = l2; *(uint4*)&Bl[n][k0 + 24] = l3;
  }
  __syncthreads();
  int wv = t >> 6, ln = t & 63;
  int mt = wv & 1;
  int nt0 = (wv >> 1) << 1;
  int lm = ln & 15, lk = ln >> 4;
  f32x4 am0 = {0,0,0,0}, am1 = {0,0,0,0}, al0 = {0,0,0,0}, al1 = {0,0,0,0};
#pragma unroll
  for (int ks = 0; ks < 4; ++ks) {
    short8x af = *(const short8x*)&Al[mt * 16 + lm][ks * 32 + lk * 8];
    short8x bm0 = *(const short8x*)&Bm[nt0 * 16 + lm][ks * 32 + lk * 8];
    short8x bm1 = *(const short8x*)&Bm[(nt0 + 1) * 16 + lm][ks * 32 + lk * 8];
    short8x bl0 = *(const short8x*)&Bl[nt0 * 16 + lm][ks * 32 + lk * 8];
    short8x bl1 = *(const short8x*)&Bl[(nt0 + 1) * 16 + lm][ks * 32 + lk * 8];
    am0 = __builtin_amdgcn_mfma_f32_16x16x32_bf16(af, bm0, am0, 0, 0, 0);
    am1 = __builtin_amdgcn_mfma_f32_16x16x32_bf16(af, bm1, am1, 0, 0, 0);
    al0 = __builtin_amdgcn_mfma_f32_16x16x32_bf16(af, bl0, al0, 0, 0, 0);
    al1 = __builtin_amdgcn_mfma_f32_16x16x32_bf16(af, bl1, al1, 0, 0, 0);
  }
  int gcol0 = bn + nt0 * 16 + lm;
  int gcol1 = gcol0 + 16;
  float bm0v = bz[gcol0], bm1v = bz[gcol1];
  float bl0v = bz[128 + gcol0], bl1v = bz[128 + gcol1];
#pragma unroll
  for (int reg = 0; reg < 4; ++reg) {
    int grow = bm + mt * 16 + lk * 4 + reg;
    size_t o0 = (size_t)grow * Hdim + gcol0;
    size_t o1 = (size_t)grow * Hdim + gcol1;
    Z[o0] = am0[reg] + bm0v + expf(al0[reg] + bl0v) * eps[o0];
    Z[o1] = am1[reg] + bm1v + expf(al1[reg] + bl1v) * eps[o1];
  }
}

// ---------------- G[128,128] += X^T @ Y  (split-K, fp32, 4x4/thread) ----------------
__global__ __launch_bounds__(256) void k_xty(const float* __restrict__ X,
                                             const float* __restrict__ Y,
                                             float* __restrict__ G, int N) {
  __shared__ float xs[8][64];
  __shared__ float ys[8][64];
  int t  = threadIdx.x;
  int tx = t & 15, ty = t >> 4;
  int qr = blockIdx.y >> 1, qc = blockIdx.y & 1;
  int KC = N / gridDim.x;
  int k0 = blockIdx.x * KC;
  int m  = t >> 7, li = t & 127;
  int lr = li >> 4, lc = (li & 15) << 2;
  const float* S = m ? Y : X;
  int coff = (m ? qc : qr) * 64;
  float acc[4][4] = {};
  for (int kb = 0; kb < KC; kb += 8) {
    float4 v = *(const float4*)(S + (size_t)(k0 + kb + lr) * Hdim + coff + lc);
    __syncthreads();
    if (m) *(float4*)&ys[lr][lc] = v; else *(float4*)&xs[lr][lc] = v;
    __syncthreads();
#pragma unroll
    for (int kk = 0; kk < 8; ++kk) {
      float4 xv = *(const float4*)&xs[kk][ty << 2];
      float4 yv = *(const float4*)&ys[kk][tx << 2];
      acc[0][0] += xv.x * yv.x; acc[0][1] += xv.x * yv.y; acc[0][2] += xv.x * yv.z; acc[0][3] += xv.x * yv.w;
      acc[1][0] += xv.y * yv.x; acc[1][1] += xv.y * yv.y; acc[1][2] += xv.y * yv.z; acc[1][3] += xv.y * yv.w;
      acc[2][0] += xv.z * yv.x; acc[2][1] += xv.z * yv.y; acc[2][2] += xv.z * yv.z; acc[2][3] += xv.z * yv.w;
      acc[3][0] += xv.w * yv.x; acc[3][1] += xv.w * yv.y; acc[3][2] += xv.w * yv.z; acc[3][3] += xv.w * yv.w;
    }
  }
  int grow = qr * 64 + (ty << 2);
  int gcol = qc * 64 + (tx << 2);
#pragma unroll
  for (int r = 0; r < 4; ++r)
#pragma unroll
    for (int c = 0; c < 4; ++c)
      atomicAdd(&G[(size_t)(grow + r) * Hdim + gcol + c], acc[r][c]);
}

extern "C" void kernel_launch(void* const* d_in, const int* in_sizes, int n_in,
                              void* d_out, int out_size, void* d_ws, size_t ws_size,
                              hipStream_t stream) {
  const int*   node_ids = (const int*)d_in[0];
  const int*   src      = (const int*)d_in[1];
  const int*   dst      = (const int*)d_in[2];
  const int*   et       = (const int*)d_in[3];
  const float* norm     = (const float*)d_in[4];
  const float* eps      = (const float*)d_in[5];
  const float* emb      = (const float*)d_in[6];
  const float* W0       = (const float*)d_in[7];
  const float* loop0    = (const float*)d_in[8];
  const float* b0       = (const float*)d_in[9];
  const float* W1       = (const float*)d_in[10];
  const float* loop1    = (const float*)d_in[11];
  const float* b1       = (const float*)d_in[12];
  const float* Wz       = (const float*)d_in[13];
  const float* bz       = (const float*)d_in[14];
  const float* Wi       = (const float*)d_in[15];
  const float* bi       = (const float*)d_in[16];
  const float* hbi      = (const float*)d_in[17];
  const float* Wo       = (const float*)d_in[18];
  const float* bo       = (const float*)d_in[19];
  const float* hbo      = (const float*)d_in[20];
  float* out = (float*)d_out;

  const int N  = in_sizes[0];   // 8192
  const int E  = in_sizes[1];   // 131072
  const int RB = in_sizes[7] / (SIq * SIq);   // NREL * NBq = 720

  char* ws = (char*)d_ws;
  const size_t MB = 1u << 20;
  const size_t KB = 1u << 10;
  float* X0   = (float*)(ws + 0 * MB);
  float* B1p  = (float*)(ws + 4 * MB);
  float* B2p  = (float*)(ws + 8 * MB);
  float* AGG  = (float*)(ws + 12 * MB);
  float* B3p  = (float*)(ws + 16 * MB);
  float* G    = (float*)(ws + 20 * MB);    // 64 KB
  int*   offp = (int*)(ws + 20 * MB + 256 * KB);
  int*   curp = (int*)(ws + 20 * MB + 512 * KB);
  int*   cntp = (int*)(ws + 20 * MB + 768 * KB);
  int*   psrc = (int*)(ws + 21 * MB);
  int*   pet  = (int*)(ws + 21 * MB + 512 * KB);
  float* pnrm = (float*)(ws + 22 * MB);
  unsigned short* Wt0 = (unsigned short*)(ws + 22 * MB + 512 * KB);  // 368 KB
  unsigned short* Wt1 = (unsigned short*)(ws + 23 * MB);             // 368 KB
  unsigned short* l0t = (unsigned short*)(ws + 24 * MB);             // 32 KB
  unsigned short* l1t = (unsigned short*)(ws + 24 * MB + 64 * KB);
  unsigned short* Wit = (unsigned short*)(ws + 24 * MB + 128 * KB);
  unsigned short* Wot = (unsigned short*)(ws + 24 * MB + 192 * KB);
  unsigned short* Wzt = (unsigned short*)(ws + 24 * MB + 256 * KB);  // 64 KB

  dim3 blk(256);

  // ---- fused preprocessing ----
  const int w0elems = RB * 256;                      // 184320
  const int gB   = (N * 32) / 256;                   // 1024
  const int wtbB = (2 * w0elems + 255) / 256;        // 1440
  const int wttB = 98304 / 256;                      // 384
  const int histB = (E + 255) / 256;                 // 512
  const int b1s = gB, b2s = gB + wtbB, b3s = gB + wtbB + wttB;
  hipMemsetAsync(cntp, 0, (size_t)N * sizeof(int), stream);
  k_pre<<<dim3(b3s + histB), blk, 0, stream>>>(
      emb, node_ids, X0, W0, Wt0, W1, Wt1, w0elems,
      loop0, loop1, Wi, Wo, Wz, l0t, l1t, Wit, Wot, Wzt,
      dst, cntp, E, b1s, b2s, b3s);
  k_scan<<<dim3(1), dim3(1024), 0, stream>>>(cntp, offp, curp, N, E);
  k_scatter<<<dim3((E + 255) / 256), blk, 0, stream>>>(src, dst, et, norm, curp,
                                                       psrc, pet, pnrm, E);

  // 2. layer-0 edge aggregation
  k_edge7<<<dim3(N / 2), blk, 0, stream>>>(X0, Wt0, offp, psrc, pet, pnrm, AGG);
  // 3. h1 = relu(agg + b0 + x0@loop0)
  k_bgemm<<<dim3(N / 32, 2), blk, 0, stream>>>(X0, l0t, nullptr, B1p, AGG, b0, N, Hdim, 1, nullptr);
  // 4. layer-1 edge aggregation
  k_edge7<<<dim3(N / 2), blk, 0, stream>>>(B1p, Wt1, offp, psrc, pet, pnrm, AGG);
  // 5. h2 = agg + b1 + h1@loop1
  k_bgemm<<<dim3(N / 32, 2), blk, 0, stream>>>(B1p, l1t, nullptr, B2p, AGG, b1, N, Hdim, 0, nullptr);
  // 6+7. z = mean + exp(log_std)*eps -> B1p
  k_bgemm_z<<<dim3(N / 32, 2), blk, 0, stream>>>(B2p, Wzt, bz, eps, B1p, N);
  // 8. C1 = z@Wi + bi + x0 -> B3p (also zero G)
  k_bgemm<<<dim3(N / 32, 2), blk, 0, stream>>>(B1p, Wit, nullptr, B3p, X0, bi, N, Hdim, 0, G);
  // 9. G1 = z^T @ C1
  k_xty<<<dim3(32, 4), blk, 0, stream>>>(B1p, B3p, G, N);
  // 10. h3 = z@G1 + hbi -> B2p
  k_bgemm<<<dim3(N / 32, 2), blk, 0, stream>>>(B1p, nullptr, G, B2p, nullptr, hbi, N, Hdim, 0, nullptr);
  // 11. C2 = h3@Wo + bo + x0 -> B3p (also zero G)
  k_bgemm<<<dim3(N / 32, 2), blk, 0, stream>>>(B2p, Wot, nullptr, B3p, X0, bo, N, Hdim, 0, G);
  // 12. G2 = h3^T @ C2
  k_xty<<<dim3(32, 4), blk, 0, stream>>>(B2p, B3p, G, N);
  // 13. out = h3@G2 + hbo
  k_bgemm<<<dim3(N / 32, 2), blk, 0, stream>>>(B2p, nullptr, G, out, nullptr, hbo, N, Hdim, 0, nullptr);
}

// Round 14
// 284.772 us; speedup vs baseline: 2.5858x; 1.2224x over previous
//
#include <hip/hip_runtime.h>
#include <hip/hip_bf16.h>
#include <math.h>

#define Hdim 128
#define NBq 8
#define SIq 16

typedef __attribute__((ext_vector_type(8))) short short8x;
typedef __attribute__((ext_vector_type(4))) float f32x4;

__device__ inline unsigned short f2b(float f) {
  unsigned int u = __float_as_uint(f);
  return (unsigned short)((u + 0x7fffu + ((u >> 16) & 1u)) >> 16);   // RNE
}
__device__ inline unsigned int pack2(float lo, float hi) {
  return (unsigned int)f2b(lo) | ((unsigned int)f2b(hi) << 16);
}

// ---------------- fused preprocessing: gather | W-bdd transpose | dense-W transpose | dst histogram ----------------
__global__ __launch_bounds__(256) void k_pre(
    const float* __restrict__ emb, const int* __restrict__ ids, float* __restrict__ x0,
    const float* __restrict__ W0, unsigned short* __restrict__ Wt0,
    const float* __restrict__ W1, unsigned short* __restrict__ Wt1, int w0elems,
    const float* __restrict__ l0, const float* __restrict__ l1,
    const float* __restrict__ Wi, const float* __restrict__ Wo, const float* __restrict__ Wz,
    unsigned short* __restrict__ l0t, unsigned short* __restrict__ l1t,
    unsigned short* __restrict__ Wit, unsigned short* __restrict__ Wot,
    unsigned short* __restrict__ Wzt,
    const int* __restrict__ dst, int* __restrict__ cnt, int E,
    int b1, int b2, int b3) {
  int bx = blockIdx.x, t = threadIdx.x;
  if (bx < b1) {
    int idx = bx * 256 + t;
    int n = idx >> 5, c4 = idx & 31;
    int s = ids[n];
    ((float4*)x0)[(size_t)n * 32 + c4] = ((const float4*)emb)[(size_t)s * 32 + c4];
  } else if (bx < b2) {
    int idx = (bx - b1) * 256 + t;
    const float* W = (idx < w0elems) ? W0 : W1;
    unsigned short* Wt = (idx < w0elems) ? Wt0 : Wt1;
    int local = (idx < w0elems) ? idx : idx - w0elems;
    int rb = local >> 8, io = local & 255;
    int i = io >> 4, o = io & 15;
    Wt[(size_t)rb * 256 + o * 16 + i] = f2b(W[(size_t)rb * 256 + i * 16 + o]);
  } else if (bx < b3) {
    int idx = (bx - b2) * 256 + t;
    if (idx < 65536) {
      int w = idx >> 14, local = idx & 16383;
      const float* in = (w == 0) ? l0 : (w == 1) ? l1 : (w == 2) ? Wi : Wo;
      unsigned short* out = (w == 0) ? l0t : (w == 1) ? l1t : (w == 2) ? Wit : Wot;
      int n = local >> 7, k = local & 127;
      out[local] = f2b(in[k * 128 + n]);
    } else {
      int local = idx - 65536;
      int n = local >> 7, k = local & 127;
      Wzt[local] = f2b(Wz[k * 256 + n]);
    }
  } else {
    int e = (bx - b3) * 256 + t;
    if (e < E) atomicAdd(&cnt[dst[e]], 1);
  }
}

// ---------------- dst CSR: scan / scatter-permute ----------------
__global__ __launch_bounds__(1024) void k_scan(const int* __restrict__ cnt,
                                               int* __restrict__ off,
                                               int* __restrict__ cur, int N, int E) {
  __shared__ int part[1024];
  int t = threadIdx.x;
  int ipt = N / 1024;
  int base = t * ipt;
  int loc[8];
  int s = 0;
  for (int i = 0; i < ipt; ++i) { loc[i] = s; s += cnt[base + i]; }
  part[t] = s;
  __syncthreads();
  for (int d = 1; d < 1024; d <<= 1) {
    int v = part[t];
    int add = (t >= d) ? part[t - d] : 0;
    __syncthreads();
    part[t] = v + add;
    __syncthreads();
  }
  int pre = (t == 0) ? 0 : part[t - 1];
  for (int i = 0; i < ipt; ++i) {
    int o = pre + loc[i];
    off[base + i] = o;
    cur[base + i] = o;
  }
  if (t == 0) off[N] = E;
}

__global__ void k_scatter(const int* __restrict__ src, const int* __restrict__ dst,
                          const int* __restrict__ et, const float* __restrict__ norm,
                          int* __restrict__ cur, int* __restrict__ psrc,
                          int* __restrict__ pet, float* __restrict__ pnorm, int E) {
  int e = blockIdx.x * blockDim.x + threadIdx.x;
  if (e >= E) return;
  int p = atomicAdd(&cur[dst[e]], 1);
  psrc[p] = src[e];
  pet[p]  = et[e];
  pnorm[p] = norm[e];
}

// ---------------- segment-reduce edge aggregation, bf16 W ----------------
// k_edge4 structure (LDS-staged x, one block/node) with a uniform-branch
// fully-unrolled fast path for full 8-edge chunks: straight-line code lets
// the scheduler cluster the 16 independent W loads (vs serialized
// load->compute per edge under the runtime-bound loop). No per-lane masks,
// no manual rotation (R7/R10 failure modes).
#define BF_LO(u) __uint_as_float((u) << 16)
#define BF_HI(u) __uint_as_float((u) & 0xffff0000u)

__device__ inline float edge_dot(const unsigned short* __restrict__ Wt,
                                 int r, int b, int o, const float* __restrict__ xrow) {
  const uint4* wp = (const uint4*)(Wt + ((size_t)r * NBq + b) * 256 + o * 16);
  uint4 wa = wp[0], wb = wp[1];
  const float4* xp = (const float4*)xrow;
  float4 x0 = xp[0], x1 = xp[1], x2 = xp[2], x3 = xp[3];
  return x0.x*BF_LO(wa.x) + x0.y*BF_HI(wa.x) + x0.z*BF_LO(wa.y) + x0.w*BF_HI(wa.y)
       + x1.x*BF_LO(wa.z) + x1.y*BF_HI(wa.z) + x1.z*BF_LO(wa.w) + x1.w*BF_HI(wa.w)
       + x2.x*BF_LO(wb.x) + x2.y*BF_HI(wb.x) + x2.z*BF_LO(wb.y) + x2.w*BF_HI(wb.y)
       + x3.x*BF_LO(wb.z) + x3.y*BF_HI(wb.z) + x3.z*BF_LO(wb.w) + x3.w*BF_HI(wb.w);
}

__global__ __launch_bounds__(128) void k_edge8(
    const float* __restrict__ h, const unsigned short* __restrict__ Wt,
    const int* __restrict__ off, const int* __restrict__ psrc,
    const int* __restrict__ pet, const float* __restrict__ pnorm,
    float* __restrict__ agg) {
  int n = blockIdx.x;
  int f = threadIdx.x;
  int b = f >> 4, o = f & 15;
  int j0 = off[n], j1 = off[n + 1];
  __shared__ float xs[8][Hdim];
  float acc = 0.f;
  for (int j = j0; j < j1; j += 8) {
    int m = j1 - j;                      // block-uniform
    if (m >= 8) {
#pragma unroll
      for (int q = 0; q < 8; ++q)
        xs[q][f] = h[(size_t)psrc[j + q] * Hdim + f];
      __syncthreads();
#pragma unroll
      for (int q = 0; q < 8; ++q) {
        int r = pet[j + q];
        float nv = pnorm[j + q];
        acc = fmaf(edge_dot(Wt, r, b, o, &xs[q][b * SIq]), nv, acc);
      }
      __syncthreads();
    } else {
      for (int q = 0; q < m; ++q)
        xs[q][f] = h[(size_t)psrc[j + q] * Hdim + f];
      __syncthreads();
      for (int q = 0; q < m; ++q) {
        int r = pet[j + q];
        float nv = pnorm[j + q];
        acc = fmaf(edge_dot(Wt, r, b, o, &xs[q][b * SIq]), nv, acc);
      }
      __syncthreads();
    }
  }
  agg[(size_t)n * Hdim + f] = acc;
}

// ---------------- MFMA bf16 GEMM: C[M,128] = A[M,128]@B + addm + bias + relu ----------------
__global__ __launch_bounds__(256) void k_bgemm(
    const float* __restrict__ A, const unsigned short* __restrict__ Bt,
    const float* __restrict__ Gsrc, float* __restrict__ C,
    const float* __restrict__ addm, const float* __restrict__ bias,
    int M, int Nc, int relu, float* __restrict__ gzero) {
  __shared__ unsigned short Al[32][136];
  __shared__ unsigned short Bl[64][136];
  int t = threadIdx.x;
  int bm = blockIdx.x * 32, bn = blockIdx.y * 64;
  if (gzero && blockIdx.x == 0 && blockIdx.y == 0) {
#pragma unroll
    for (int i = 0; i < 16; ++i)
      ((float4*)gzero)[t + 256 * i] = make_float4(0.f, 0.f, 0.f, 0.f);
  }
  {
    int r = t >> 3, c0 = (t & 7) << 4;
    const float4* ap = (const float4*)(A + (size_t)(bm + r) * Hdim + c0);
    float4 a0 = ap[0], a1 = ap[1], a2 = ap[2], a3 = ap[3];
    uint4 p0 = { pack2(a0.x, a0.y), pack2(a0.z, a0.w), pack2(a1.x, a1.y), pack2(a1.z, a1.w) };
    uint4 p1 = { pack2(a2.x, a2.y), pack2(a2.z, a2.w), pack2(a3.x, a3.y), pack2(a3.z, a3.w) };
    *(uint4*)&Al[r][c0]     = p0;
    *(uint4*)&Al[r][c0 + 8] = p1;
  }
  if (Bt) {
    int n = t >> 2, k0 = (t & 3) << 5;
    const uint4* bp = (const uint4*)(Bt + (size_t)(bn + n) * Hdim + k0);
    uint4 b0 = bp[0], b1 = bp[1], b2 = bp[2], b3 = bp[3];
    *(uint4*)&Bl[n][k0]      = b0;
    *(uint4*)&Bl[n][k0 + 8]  = b1;
    *(uint4*)&Bl[n][k0 + 16] = b2;
    *(uint4*)&Bl[n][k0 + 24] = b3;
  } else {
    int n = t & 63, kb = (t >> 6) << 5;
    for (int i = 0; i < 32; ++i) {
      int k = kb + i;
      Bl[n][k] = f2b(Gsrc[(size_t)k * 128 + bn + n]);
    }
  }
  __syncthreads();
  int wv = t >> 6, ln = t & 63;
  int mt = wv & 1;
  int nt0 = (wv >> 1) << 1;
  int lm = ln & 15, lk = ln >> 4;
  f32x4 acc0 = {0.f, 0.f, 0.f, 0.f}, acc1 = {0.f, 0.f, 0.f, 0.f};
#pragma unroll
  for (int ks = 0; ks < 4; ++ks) {
    short8x af = *(const short8x*)&Al[mt * 16 + lm][ks * 32 + lk * 8];
    short8x bf0 = *(const short8x*)&Bl[nt0 * 16 + lm][ks * 32 + lk * 8];
    short8x bf1 = *(const short8x*)&Bl[(nt0 + 1) * 16 + lm][ks * 32 + lk * 8];
    acc0 = __builtin_amdgcn_mfma_f32_16x16x32_bf16(af, bf0, acc0, 0, 0, 0);
    acc1 = __builtin_amdgcn_mfma_f32_16x16x32_bf16(af, bf1, acc1, 0, 0, 0);
  }
  int gcol0 = bn + nt0 * 16 + lm;
  int gcol1 = gcol0 + 16;
  float b0v = bias ? bias[gcol0] : 0.f;
  float b1v = bias ? bias[gcol1] : 0.f;
#pragma unroll
  for (int reg = 0; reg < 4; ++reg) {
    int grow = bm + mt * 16 + lk * 4 + reg;
    size_t o0 = (size_t)grow * Nc + gcol0;
    size_t o1 = (size_t)grow * Nc + gcol1;
    float v0 = acc0[reg] + b0v;
    float v1 = acc1[reg] + b1v;
    if (addm) { v0 += addm[o0]; v1 += addm[o1]; }
    if (relu) { v0 = fmaxf(v0, 0.f); v1 = fmaxf(v1, 0.f); }
    C[o0] = v0;
    C[o1] = v1;
  }
}

// ---------------- MFMA bf16 zml GEMM fused with reparameterization ----------------
__global__ __launch_bounds__(256) void k_bgemm_z(
    const float* __restrict__ A, const unsigned short* __restrict__ Wzt,
    const float* __restrict__ bz, const float* __restrict__ eps,
    float* __restrict__ Z, int M) {
  __shared__ unsigned short Al[32][136];
  __shared__ unsigned short Bm[64][136];
  __shared__ unsigned short Bl[64][136];
  int t = threadIdx.x;
  int bm = blockIdx.x * 32, bn = blockIdx.y * 64;
  {
    int r = t >> 3, c0 = (t & 7) << 4;
    const float4* ap = (const float4*)(A + (size_t)(bm + r) * Hdim + c0);
    float4 a0 = ap[0], a1 = ap[1], a2 = ap[2], a3 = ap[3];
    uint4 p0 = { pack2(a0.x, a0.y), pack2(a0.z, a0.w), pack2(a1.x, a1.y), pack2(a1.z, a1.w) };
    uint4 p1 = { pack2(a2.x, a2.y), pack2(a2.z, a2.w), pack2(a3.x, a3.y), pack2(a3.z, a3.w) };
    *(uint4*)&Al[r][c0]     = p0;
    *(uint4*)&Al[r][c0 + 8] = p1;
  }
  {
    int n = t >> 2, k0 = (t & 3) << 5;
    const uint4* mp = (const uint4*)(Wzt + (size_t)(bn + n) * Hdim + k0);
    const uint4* lp = (const uint4*)(Wzt + (size_t)(bn + 128 + n) * Hdim + k0);
    uint4 m0 = mp[0], m1 = mp[1], m2 = mp[2], m3 = mp[3];
    uint4 l0 = lp[0], l1 = lp[1], l2 = lp[2], l3 = lp[3];
    *(uint4*)&Bm[n][k0]      = m0; *(uint4*)&Bm[n][k0 + 8]  = m1;
    *(uint4*)&Bm[n][k0 + 16] = m2; *(uint4*)&Bm[n][k0 + 24] = m3;
    *(uint4*)&Bl[n][k0]      = l0; *(uint4*)&Bl[n][k0 + 8]  = l1;
    *(uint4*)&Bl[n][k0 + 16] = l2; *(uint4*)&Bl[n][k0 + 24] = l3;
  }
  __syncthreads();
  int wv = t >> 6, ln = t & 63;
  int mt = wv & 1;
  int nt0 = (wv >> 1) << 1;
  int lm = ln & 15, lk = ln >> 4;
  f32x4 am0 = {0,0,0,0}, am1 = {0,0,0,0}, al0 = {0,0,0,0}, al1 = {0,0,0,0};
#pragma unroll
  for (int ks = 0; ks < 4; ++ks) {
    short8x af = *(const short8x*)&Al[mt * 16 + lm][ks * 32 + lk * 8];
    short8x bm0 = *(const short8x*)&Bm[nt0 * 16 + lm][ks * 32 + lk * 8];
    short8x bm1 = *(const short8x*)&Bm[(nt0 + 1) * 16 + lm][ks * 32 + lk * 8];
    short8x bl0 = *(const short8x*)&Bl[nt0 * 16 + lm][ks * 32 + lk * 8];
    short8x bl1 = *(const short8x*)&Bl[(nt0 + 1) * 16 + lm][ks * 32 + lk * 8];
    am0 = __builtin_amdgcn_mfma_f32_16x16x32_bf16(af, bm0, am0, 0, 0, 0);
    am1 = __builtin_amdgcn_mfma_f32_16x16x32_bf16(af, bm1, am1, 0, 0, 0);
    al0 = __builtin_amdgcn_mfma_f32_16x16x32_bf16(af, bl0, al0, 0, 0, 0);
    al1 = __builtin_amdgcn_mfma_f32_16x16x32_bf16(af, bl1, al1, 0, 0, 0);
  }
  int gcol0 = bn + nt0 * 16 + lm;
  int gcol1 = gcol0 + 16;
  float bm0v = bz[gcol0], bm1v = bz[gcol1];
  float bl0v = bz[128 + gcol0], bl1v = bz[128 + gcol1];
#pragma unroll
  for (int reg = 0; reg < 4; ++reg) {
    int grow = bm + mt * 16 + lk * 4 + reg;
    size_t o0 = (size_t)grow * Hdim + gcol0;
    size_t o1 = (size_t)grow * Hdim + gcol1;
    Z[o0] = am0[reg] + bm0v + expf(al0[reg] + bl0v) * eps[o0];
    Z[o1] = am1[reg] + bm1v + expf(al1[reg] + bl1v) * eps[o1];
  }
}

// ---------------- G[128,128] += X^T @ Y  (split-K, fp32, 4x4/thread) ----------------
__global__ __launch_bounds__(256) void k_xty(const float* __restrict__ X,
                                             const float* __restrict__ Y,
                                             float* __restrict__ G, int N) {
  __shared__ float xs[8][64];
  __shared__ float ys[8][64];
  int t  = threadIdx.x;
  int tx = t & 15, ty = t >> 4;
  int qr = blockIdx.y >> 1, qc = blockIdx.y & 1;
  int KC = N / gridDim.x;
  int k0 = blockIdx.x * KC;
  int m  = t >> 7, li = t & 127;
  int lr = li >> 4, lc = (li & 15) << 2;
  const float* S = m ? Y : X;
  int coff = (m ? qc : qr) * 64;
  float acc[4][4] = {};
  for (int kb = 0; kb < KC; kb += 8) {
    float4 v = *(const float4*)(S + (size_t)(k0 + kb + lr) * Hdim + coff + lc);
    __syncthreads();
    if (m) *(float4*)&ys[lr][lc] = v; else *(float4*)&xs[lr][lc] = v;
    __syncthreads();
#pragma unroll
    for (int kk = 0; kk < 8; ++kk) {
      float4 xv = *(const float4*)&xs[kk][ty << 2];
      float4 yv = *(const float4*)&ys[kk][tx << 2];
      acc[0][0] += xv.x * yv.x; acc[0][1] += xv.x * yv.y; acc[0][2] += xv.x * yv.z; acc[0][3] += xv.x * yv.w;
      acc[1][0] += xv.y * yv.x; acc[1][1] += xv.y * yv.y; acc[1][2] += xv.y * yv.z; acc[1][3] += xv.y * yv.w;
      acc[2][0] += xv.z * yv.x; acc[2][1] += xv.z * yv.y; acc[2][2] += xv.z * yv.z; acc[2][3] += xv.z * yv.w;
      acc[3][0] += xv.w * yv.x; acc[3][1] += xv.w * yv.y; acc[3][2] += xv.w * yv.z; acc[3][3] += xv.w * yv.w;
    }
  }
  int grow = qr * 64 + (ty << 2);
  int gcol = qc * 64 + (tx << 2);
#pragma unroll
  for (int r = 0; r < 4; ++r)
#pragma unroll
    for (int c = 0; c < 4; ++c)
      atomicAdd(&G[(size_t)(grow + r) * Hdim + gcol + c], acc[r][c]);
}

extern "C" void kernel_launch(void* const* d_in, const int* in_sizes, int n_in,
                              void* d_out, int out_size, void* d_ws, size_t ws_size,
                              hipStream_t stream) {
  const int*   node_ids = (const int*)d_in[0];
  const int*   src      = (const int*)d_in[1];
  const int*   dst      = (const int*)d_in[2];
  const int*   et       = (const int*)d_in[3];
  const float* norm     = (const float*)d_in[4];
  const float* eps      = (const float*)d_in[5];
  const float* emb      = (const float*)d_in[6];
  const float* W0       = (const float*)d_in[7];
  const float* loop0    = (const float*)d_in[8];
  const float* b0       = (const float*)d_in[9];
  const float* W1       = (const float*)d_in[10];
  const float* loop1    = (const float*)d_in[11];
  const float* b1       = (const float*)d_in[12];
  const float* Wz       = (const float*)d_in[13];
  const float* bz       = (const float*)d_in[14];
  const float* Wi       = (const float*)d_in[15];
  const float* bi       = (const float*)d_in[16];
  const float* hbi      = (const float*)d_in[17];
  const float* Wo       = (const float*)d_in[18];
  const float* bo       = (const float*)d_in[19];
  const float* hbo      = (const float*)d_in[20];
  float* out = (float*)d_out;

  const int N  = in_sizes[0];   // 8192
  const int E  = in_sizes[1];   // 131072
  const int RB = in_sizes[7] / (SIq * SIq);   // NREL * NBq = 720

  char* ws = (char*)d_ws;
  const size_t MB = 1u << 20;
  const size_t KB = 1u << 10;
  float* X0   = (float*)(ws + 0 * MB);
  float* B1p  = (float*)(ws + 4 * MB);
  float* B2p  = (float*)(ws + 8 * MB);
  float* AGG  = (float*)(ws + 12 * MB);
  float* B3p  = (float*)(ws + 16 * MB);
  float* G    = (float*)(ws + 20 * MB);    // 64 KB
  int*   offp = (int*)(ws + 20 * MB + 256 * KB);
  int*   curp = (int*)(ws + 20 * MB + 512 * KB);
  int*   cntp = (int*)(ws + 20 * MB + 768 * KB);
  int*   psrc = (int*)(ws + 21 * MB);
  int*   pet  = (int*)(ws + 21 * MB + 512 * KB);
  float* pnrm = (float*)(ws + 22 * MB);
  unsigned short* Wt0 = (unsigned short*)(ws + 22 * MB + 512 * KB);  // 368 KB
  unsigned short* Wt1 = (unsigned short*)(ws + 23 * MB);             // 368 KB
  unsigned short* l0t = (unsigned short*)(ws + 24 * MB);             // 32 KB
  unsigned short* l1t = (unsigned short*)(ws + 24 * MB + 64 * KB);
  unsigned short* Wit = (unsigned short*)(ws + 24 * MB + 128 * KB);
  unsigned short* Wot = (unsigned short*)(ws + 24 * MB + 192 * KB);
  unsigned short* Wzt = (unsigned short*)(ws + 24 * MB + 256 * KB);  // 64 KB

  dim3 blk(256);

  // ---- fused preprocessing ----
  const int w0elems = RB * 256;                      // 184320
  const int gB   = (N * 32) / 256;                   // 1024
  const int wtbB = (2 * w0elems + 255) / 256;        // 1440
  const int wttB = 98304 / 256;                      // 384
  const int histB = (E + 255) / 256;                 // 512
  const int b1s = gB, b2s = gB + wtbB, b3s = gB + wtbB + wttB;
  hipMemsetAsync(cntp, 0, (size_t)N * sizeof(int), stream);
  k_pre<<<dim3(b3s + histB), blk, 0, stream>>>(
      emb, node_ids, X0, W0, Wt0, W1, Wt1, w0elems,
      loop0, loop1, Wi, Wo, Wz, l0t, l1t, Wit, Wot, Wzt,
      dst, cntp, E, b1s, b2s, b3s);
  k_scan<<<dim3(1), dim3(1024), 0, stream>>>(cntp, offp, curp, N, E);
  k_scatter<<<dim3((E + 255) / 256), blk, 0, stream>>>(src, dst, et, norm, curp,
                                                       psrc, pet, pnrm, E);

  // 2. layer-0 edge aggregation
  k_edge8<<<dim3(N), dim3(128), 0, stream>>>(X0, Wt0, offp, psrc, pet, pnrm, AGG);
  // 3. h1 = relu(agg + b0 + x0@loop0)
  k_bgemm<<<dim3(N / 32, 2), blk, 0, stream>>>(X0, l0t, nullptr, B1p, AGG, b0, N, Hdim, 1, nullptr);
  // 4. layer-1 edge aggregation
  k_edge8<<<dim3(N), dim3(128), 0, stream>>>(B1p, Wt1, offp, psrc, pet, pnrm, AGG);
  // 5. h2 = agg + b1 + h1@loop1
  k_bgemm<<<dim3(N / 32, 2), blk, 0, stream>>>(B1p, l1t, nullptr, B2p, AGG, b1, N, Hdim, 0, nullptr);
  // 6+7. z = mean + exp(log_std)*eps -> B1p
  k_bgemm_z<<<dim3(N / 32, 2), blk, 0, stream>>>(B2p, Wzt, bz, eps, B1p, N);
  // 8. C1 = z@Wi + bi + x0 -> B3p (also zero G)
  k_bgemm<<<dim3(N / 32, 2), blk, 0, stream>>>(B1p, Wit, nullptr, B3p, X0, bi, N, Hdim, 0, G);
  // 9. G1 = z^T @ C1
  k_xty<<<dim3(32, 4), blk, 0, stream>>>(B1p, B3p, G, N);
  // 10. h3 = z@G1 + hbi -> B2p
  k_bgemm<<<dim3(N / 32, 2), blk, 0, stream>>>(B1p, nullptr, G, B2p, nullptr, hbi, N, Hdim, 0, nullptr);
  // 11. C2 = h3@Wo + bo + x0 -> B3p (also zero G)
  k_bgemm<<<dim3(N / 32, 2), blk, 0, stream>>>(B2p, Wot, nullptr, B3p, X0, bo, N, Hdim, 0, G);
  // 12. G2 = h3^T @ C2
  k_xty<<<dim3(32, 4), blk, 0, stream>>>(B2p, B3p, G, N);
  // 13. out = h3@G2 + hbo
  k_bgemm<<<dim3(N / 32, 2), blk, 0, stream>>>(B2p, nullptr, G, out, nullptr, hbo, N, Hdim, 0, nullptr);
}